// Round 1
// baseline (195.188 us; speedup 1.0000x reference)
//
#include <hip/hip_runtime.h>
#include <math.h>

constexpr int B_ = 8, N_ = 1024, F_ = 256, H_ = 4, U_ = 256;
constexpr int BH_ = B_ * H_;
constexpr int CH_ = 64;          // scan chunk length
constexpr int NCH_ = N_ / CH_;   // 16 chunks

// ---------------- K0: c_src[h,f] = sum_u W[h,f,u]*a_src[h,u]; same for dst ----
__global__ void k0_cvec(const float* __restrict__ W, const float* __restrict__ asr,
                        const float* __restrict__ ads, float* __restrict__ c_src,
                        float* __restrict__ c_dst) {
    int h = blockIdx.x;          // 0..H-1
    int f = threadIdx.x;         // 0..F-1
    const float* Wrow = W + ((size_t)h * F_ + f) * U_;
    const float* av = asr + (size_t)h * U_;   // a_src [H,U,1]
    const float* bv = ads + (size_t)h * U_;
    float s = 0.f, d = 0.f;
    for (int u = 0; u < U_; ++u) { float w = Wrow[u]; s += w * av[u]; d += w * bv[u]; }
    c_src[h * F_ + f] = s;
    c_dst[h * F_ + f] = d;
}

// ---------------- K1: h[bh,n,u] = sum_f x[b,n,f] * W[h,f,u]  (fp32 tiled GEMM) --
__global__ __launch_bounds__(256) void k1_proj(const float* __restrict__ x,
                                               const float* __restrict__ W,
                                               float* __restrict__ hbuf) {
    __shared__ float As[32][65];   // [k][n], padded
    __shared__ float Bs[32][64];   // [k][u]
    int bh = blockIdx.z, b = bh >> 2, hh = bh & 3;
    int n0 = blockIdx.x * 64, u0 = blockIdx.y * 64;
    int tid = threadIdx.x, tx = tid & 15, ty = tid >> 4;
    const float* xb = x + ((size_t)b * N_ + n0) * F_;
    const float* Wb = W + (size_t)hh * F_ * U_ + u0;
    float acc[4][4] = {};
    for (int k0 = 0; k0 < F_; k0 += 32) {
        #pragma unroll
        for (int l = 0; l < 8; ++l) {
            int e = tid + l * 256;
            int row = e >> 5, kk = e & 31;
            As[kk][row] = xb[(size_t)row * F_ + k0 + kk];
        }
        #pragma unroll
        for (int l = 0; l < 8; ++l) {
            int e = tid + l * 256;
            int kk = e >> 6, uu = e & 63;
            Bs[kk][uu] = Wb[(size_t)(k0 + kk) * U_ + uu];
        }
        __syncthreads();
        #pragma unroll
        for (int kk = 0; kk < 32; ++kk) {
            float a0 = As[kk][ty*4+0], a1 = As[kk][ty*4+1], a2 = As[kk][ty*4+2], a3 = As[kk][ty*4+3];
            float b0 = Bs[kk][tx*4+0], b1 = Bs[kk][tx*4+1], b2 = Bs[kk][tx*4+2], b3 = Bs[kk][tx*4+3];
            acc[0][0] += a0*b0; acc[0][1] += a0*b1; acc[0][2] += a0*b2; acc[0][3] += a0*b3;
            acc[1][0] += a1*b0; acc[1][1] += a1*b1; acc[1][2] += a1*b2; acc[1][3] += a1*b3;
            acc[2][0] += a2*b0; acc[2][1] += a2*b1; acc[2][2] += a2*b2; acc[2][3] += a2*b3;
            acc[3][0] += a3*b0; acc[3][1] += a3*b1; acc[3][2] += a3*b2; acc[3][3] += a3*b3;
        }
        __syncthreads();
    }
    float* hp = hbuf + ((size_t)bh * N_ + n0) * U_ + u0;
    #pragma unroll
    for (int i = 0; i < 4; ++i) {
        float4 v = make_float4(acc[i][0], acc[i][1], acc[i][2], acc[i][3]);
        *(float4*)&hp[(size_t)(ty*4 + i) * U_ + tx*4] = v;
    }
}

// ---------------- K1b: src[bh,n] = x[b,n,:].c_src[h,:]; same dst (wave per row) -
__global__ __launch_bounds__(256) void k1b_srcdst(const float* __restrict__ x,
                                                  const float* __restrict__ c_src,
                                                  const float* __restrict__ c_dst,
                                                  float* __restrict__ srcv,
                                                  float* __restrict__ dstv) {
    int tid = threadIdx.x;
    int lane = tid & 63, w = tid >> 6;
    int row = blockIdx.x * 4 + w;           // 0..B*N-1
    int b = row >> 10, n = row & 1023;
    const float4 x4 = *(const float4*)(x + (size_t)row * F_ + lane * 4);
    #pragma unroll
    for (int hh = 0; hh < H_; ++hh) {
        float4 c4 = *(const float4*)(c_src + hh * F_ + lane * 4);
        float s = x4.x*c4.x + x4.y*c4.y + x4.z*c4.z + x4.w*c4.w;
        #pragma unroll
        for (int off = 32; off; off >>= 1) s += __shfl_xor(s, off);
        float4 d4 = *(const float4*)(c_dst + hh * F_ + lane * 4);
        float d = x4.x*d4.x + x4.y*d4.y + x4.z*d4.z + x4.w*d4.w;
        #pragma unroll
        for (int off = 32; off; off >>= 1) d += __shfl_xor(d, off);
        if (lane == 0) {
            srcv[(size_t)(b * H_ + hh) * N_ + n] = s;
            dstv[(size_t)(b * H_ + hh) * N_ + n] = d;
        }
    }
}

// ---------------- K2: per-(b,h) bitonic sort of dst values (keys) + index ------
__global__ __launch_bounds__(1024) void k2_sort(const float* __restrict__ dstv,
                                                float* __restrict__ dvs,
                                                int* __restrict__ perm) {
    __shared__ float key[N_];
    __shared__ int   idx[N_];
    int bh = blockIdx.x;
    int t = threadIdx.x;
    key[t] = dstv[(size_t)bh * N_ + t];
    idx[t] = t;
    __syncthreads();
    for (int k = 2; k <= N_; k <<= 1) {
        for (int j = k >> 1; j > 0; j >>= 1) {
            int p = t ^ j;
            if (p > t) {
                float a = key[t], bb = key[p];
                bool up = ((t & k) == 0);
                if (up ? (a > bb) : (a < bb)) {
                    key[t] = bb; key[p] = a;
                    int ti = idx[t]; idx[t] = idx[p]; idx[p] = ti;
                }
            }
            __syncthreads();
        }
    }
    dvs[(size_t)bh * N_ + t] = key[t];
    perm[(size_t)bh * N_ + t] = idx[t];
}

// ---------------- K3a: per-chunk partial sums of w1*h, w2*h ---------------------
__global__ __launch_bounds__(256) void k3a_partial(const float* __restrict__ hbuf,
                                                   const float* __restrict__ dvs,
                                                   const int* __restrict__ perm,
                                                   float* __restrict__ cT1, float* __restrict__ cT2,
                                                   float* __restrict__ cZ1, float* __restrict__ cZ2) {
    int bh = blockIdx.x >> 4;
    int c  = blockIdx.x & 15;
    int u  = threadIdx.x;
    __shared__ float w1s[CH_], w2s[CH_];
    __shared__ int   ps[CH_];
    if (u < CH_) {
        float v = dvs[(size_t)bh * N_ + c * CH_ + u];
        w1s[u] = expf(v);
        w2s[u] = expf(0.2f * v);
        ps[u]  = perm[(size_t)bh * N_ + c * CH_ + u];
    }
    __syncthreads();
    const float* hb = hbuf + (size_t)bh * N_ * U_;
    float a1 = 0.f, a2 = 0.f, z1 = 0.f, z2 = 0.f;
    #pragma unroll 8
    for (int r = 0; r < CH_; ++r) {
        float v = hb[(size_t)ps[r] * U_ + u];
        a1 += w1s[r] * v;
        a2 += w2s[r] * v;
        z1 += w1s[r];
        z2 += w2s[r];
    }
    cT1[(size_t)(bh * NCH_ + c) * U_ + u] = a1;
    cT2[(size_t)(bh * NCH_ + c) * U_ + u] = a2;
    if (u == 0) { cZ1[bh * NCH_ + c] = z1; cZ2[bh * NCH_ + c] = z2; }
}

// ---------------- K3b: chunk-level exclusive prefix (T2) / suffix (T1) bases ----
__global__ __launch_bounds__(256) void k3b_combine(const float* __restrict__ cT1, const float* __restrict__ cT2,
                                                   const float* __restrict__ cZ1, const float* __restrict__ cZ2,
                                                   float* __restrict__ b1, float* __restrict__ b2,
                                                   float* __restrict__ bz1, float* __restrict__ bz2) {
    int bh = blockIdx.x;
    int u = threadIdx.x;
    float acc2 = 0.f;
    for (int c = 0; c < NCH_; ++c) {
        b2[(size_t)(bh * NCH_ + c) * U_ + u] = acc2;
        acc2 += cT2[(size_t)(bh * NCH_ + c) * U_ + u];
    }
    float acc1 = 0.f;
    for (int c = NCH_ - 1; c >= 0; --c) {
        b1[(size_t)(bh * NCH_ + c) * U_ + u] = acc1;
        acc1 += cT1[(size_t)(bh * NCH_ + c) * U_ + u];
    }
    if (u == 0) {
        float z2 = 0.f;
        for (int c = 0; c < NCH_; ++c) { bz2[bh * NCH_ + c] = z2; z2 += cZ2[bh * NCH_ + c]; }
        float z1 = 0.f;
        for (int c = NCH_ - 1; c >= 0; --c) { bz1[bh * NCH_ + c] = z1; z1 += cZ1[bh * NCH_ + c]; }
    }
}

// ---------------- K3c: emit full S1 (suffix incl), S2 (prefix excl), Z1, Z2 -----
__global__ __launch_bounds__(256) void k3c_emit(const float* __restrict__ hbuf,
                                                const float* __restrict__ dvs,
                                                const int* __restrict__ perm,
                                                const float* __restrict__ b1, const float* __restrict__ b2,
                                                const float* __restrict__ bz1, const float* __restrict__ bz2,
                                                float* __restrict__ S1, float* __restrict__ S2,
                                                float* __restrict__ Z1, float* __restrict__ Z2) {
    int bh = blockIdx.x >> 4;
    int c  = blockIdx.x & 15;
    int u  = threadIdx.x;
    __shared__ float w1s[CH_], w2s[CH_];
    __shared__ int   ps[CH_];
    if (u < CH_) {
        float v = dvs[(size_t)bh * N_ + c * CH_ + u];
        w1s[u] = expf(v);
        w2s[u] = expf(0.2f * v);
        ps[u]  = perm[(size_t)bh * N_ + c * CH_ + u];
    }
    __syncthreads();
    const float* hb = hbuf + (size_t)bh * N_ * U_;
    float vals[CH_];
    #pragma unroll
    for (int r = 0; r < CH_; ++r) vals[r] = hb[(size_t)ps[r] * U_ + u];

    size_t rowbase = (size_t)bh * (N_ + 1);
    size_t base = (rowbase + (size_t)c * CH_) * U_;
    float* S2p = S2 + base;
    float* S1p = S1 + base;

    float acc2 = b2[(size_t)(bh * NCH_ + c) * U_ + u];
    float az2  = bz2[bh * NCH_ + c];
    #pragma unroll
    for (int r = 0; r < CH_; ++r) {
        S2p[(size_t)r * U_ + u] = acc2;
        if (u == 0) Z2[rowbase + c * CH_ + r] = az2;
        acc2 += w2s[r] * vals[r];
        az2  += w2s[r];
    }
    if (c == NCH_ - 1) {
        S2p[(size_t)CH_ * U_ + u] = acc2;          // row N (all branch-2)
        if (u == 0) Z2[rowbase + N_] = az2;
        S1[(rowbase + N_) * U_ + u] = 0.f;         // row N suffix empty
        if (u == 0) Z1[rowbase + N_] = 0.f;
    }

    float acc1 = b1[(size_t)(bh * NCH_ + c) * U_ + u];
    float az1  = bz1[bh * NCH_ + c];
    #pragma unroll
    for (int r = CH_ - 1; r >= 0; --r) {
        acc1 += w1s[r] * vals[r];
        az1  += w1s[r];
        S1p[(size_t)r * U_ + u] = acc1;
        if (u == 0) Z1[rowbase + c * CH_ + r] = az1;
    }
}

// ---------------- K4: per row binary search + combine + write -------------------
__global__ __launch_bounds__(256) void k4_out(const float* __restrict__ srcv,
                                              const float* __restrict__ dvs,
                                              const float* __restrict__ S1, const float* __restrict__ S2,
                                              const float* __restrict__ Z1, const float* __restrict__ Z2,
                                              float* __restrict__ out) {
    int bh = blockIdx.x >> 4;
    int ic = blockIdx.x & 15;
    int b = bh >> 2, hh = bh & 3;
    int u = threadIdx.x;
    __shared__ float dv[N_];
    #pragma unroll
    for (int l = 0; l < 4; ++l) dv[u + l * 256] = dvs[(size_t)bh * N_ + u + l * 256];
    __syncthreads();
    size_t rowbase = (size_t)bh * (N_ + 1);
    for (int ii = 0; ii < 64; ++ii) {
        int i = ic * 64 + ii;
        float s = srcv[(size_t)bh * N_ + i];
        float t = -s;
        int lo = 0, hi = N_;
        while (lo < hi) {                 // pos = count(dv <= -s), uniform across wave
            int mid = (lo + hi) >> 1;
            if (dv[mid] <= t) lo = mid + 1; else hi = mid;
        }
        int pos = lo;
        float e8 = expf(0.8f * s);
        size_t rb = (rowbase + pos) * U_;
        float num = e8 * S1[rb + u] + S2[rb + u];
        float den = e8 * Z1[rowbase + pos] + Z2[rowbase + pos];
        out[((size_t)b * N_ + i) * (H_ * U_) + hh * U_ + u] = num / den;
    }
}

// ---------------- host launch ----------------------------------------------------
extern "C" void kernel_launch(void* const* d_in, const int* in_sizes, int n_in,
                              void* d_out, int out_size, void* d_ws, size_t ws_size,
                              hipStream_t stream) {
    const float* x    = (const float*)d_in[0];
    const float* W    = (const float*)d_in[1];
    const float* asr  = (const float*)d_in[2];
    const float* ads  = (const float*)d_in[3];
    float* out = (float*)d_out;

    char* ws = (char*)d_ws;
    size_t off = 0;
    auto alloc = [&](size_t nfloats) -> float* {
        float* p = (float*)(ws + off);
        off += ((nfloats * 4 + 255) / 256) * 256;
        return p;
    };
    float* hbuf  = alloc((size_t)BH_ * N_ * U_);          // 33.5 MB
    float* srcv  = alloc((size_t)BH_ * N_);
    float* dstv  = alloc((size_t)BH_ * N_);
    float* c_src = alloc(H_ * F_);
    float* c_dst = alloc(H_ * F_);
    float* dvs   = alloc((size_t)BH_ * N_);
    int*   perm  = (int*)alloc((size_t)BH_ * N_);
    float* cT1   = alloc((size_t)BH_ * NCH_ * U_);
    float* cT2   = alloc((size_t)BH_ * NCH_ * U_);
    float* cZ1   = alloc(BH_ * NCH_);
    float* cZ2   = alloc(BH_ * NCH_);
    float* b1    = alloc((size_t)BH_ * NCH_ * U_);
    float* b2    = alloc((size_t)BH_ * NCH_ * U_);
    float* bz1   = alloc(BH_ * NCH_);
    float* bz2   = alloc(BH_ * NCH_);
    float* S1    = alloc((size_t)BH_ * (N_ + 1) * U_);    // 33.6 MB
    float* S2    = alloc((size_t)BH_ * (N_ + 1) * U_);    // 33.6 MB
    float* Z1    = alloc((size_t)BH_ * (N_ + 1));
    float* Z2    = alloc((size_t)BH_ * (N_ + 1));
    (void)ws_size; (void)in_sizes; (void)n_in; (void)out_size;

    k0_cvec<<<H_, 256, 0, stream>>>(W, asr, ads, c_src, c_dst);
    k1_proj<<<dim3(N_/64, U_/64, BH_), 256, 0, stream>>>(x, W, hbuf);
    k1b_srcdst<<<(B_*N_)/4, 256, 0, stream>>>(x, c_src, c_dst, srcv, dstv);
    k2_sort<<<BH_, 1024, 0, stream>>>(dstv, dvs, perm);
    k3a_partial<<<BH_*NCH_, 256, 0, stream>>>(hbuf, dvs, perm, cT1, cT2, cZ1, cZ2);
    k3b_combine<<<BH_, 256, 0, stream>>>(cT1, cT2, cZ1, cZ2, b1, b2, bz1, bz2);
    k3c_emit<<<BH_*NCH_, 256, 0, stream>>>(hbuf, dvs, perm, b1, b2, bz1, bz2, S1, S2, Z1, Z2);
    k4_out<<<BH_*NCH_, 256, 0, stream>>>(srcv, dvs, S1, S2, Z1, Z2, out);
}

// Round 2
// 162.812 us; speedup vs baseline: 1.1989x; 1.1989x over previous
//
#include <hip/hip_runtime.h>
#include <math.h>

constexpr int B_ = 8, N_ = 1024, F_ = 256, H_ = 4, U_ = 256;
constexpr int BH_ = B_ * H_;
constexpr int CH_ = 64;          // scan chunk length
constexpr int NCH_ = N_ / CH_;   // 16 chunks
constexpr int M_ = B_ * N_;      // 8192 GEMM rows per head

typedef short short8 __attribute__((ext_vector_type(8)));
typedef float floatx4 __attribute__((ext_vector_type(4)));

__device__ inline unsigned short f2bf(float f) {
    unsigned u = __float_as_uint(f);
    u += 0x7fff + ((u >> 16) & 1);          // round-to-nearest-even
    return (unsigned short)(u >> 16);
}
__device__ inline float bf2f(unsigned short s) { return __uint_as_float(((unsigned)s) << 16); }

__device__ inline void gload_lds16(const void* g, void* l) {
    __builtin_amdgcn_global_load_lds(
        (const __attribute__((address_space(1))) void*)g,
        (__attribute__((address_space(3))) void*)(unsigned)(uintptr_t)l,
        16, 0, 0);
}

// ---------------- conv: split fp32 -> bf16 hi + bf16 lo (elementwise, x) -------
__global__ __launch_bounds__(256) void conv_split(const float* __restrict__ in,
                                                  unsigned short* __restrict__ hi,
                                                  unsigned short* __restrict__ lo) {
    int i = blockIdx.x * 256 + threadIdx.x;
    float4 v = ((const float4*)in)[i];
    ushort4 h, l;
    h.x = f2bf(v.x); l.x = f2bf(v.x - bf2f(h.x));
    h.y = f2bf(v.y); l.y = f2bf(v.y - bf2f(h.y));
    h.z = f2bf(v.z); l.z = f2bf(v.z - bf2f(h.z));
    h.w = f2bf(v.w); l.w = f2bf(v.w - bf2f(h.w));
    ((ushort4*)hi)[i] = h;
    ((ushort4*)lo)[i] = l;
}

// ---------------- convT: W[h,f,u] fp32 -> WT[h,u,f] bf16 hi/lo (tiled transpose)
__global__ __launch_bounds__(256) void conv_wT(const float* __restrict__ W,
                                               unsigned short* __restrict__ whT,
                                               unsigned short* __restrict__ wlT) {
    __shared__ float t[64][65];
    int h = blockIdx.z, f0 = blockIdx.x * 64, u0 = blockIdx.y * 64;
    int tid = threadIdx.x;
    int c = tid & 63, rbase = tid >> 6;
    #pragma unroll
    for (int rr = 0; rr < 16; ++rr) {
        int r = rr * 4 + rbase;
        t[r][c] = W[((size_t)(h * F_ + f0 + r)) * U_ + u0 + c];
    }
    __syncthreads();
    #pragma unroll
    for (int rr = 0; rr < 16; ++rr) {
        int r = rr * 4 + rbase;                 // u-local
        float v = t[c][r];                      // W[f0+c][u0+r]
        unsigned short hb = f2bf(v);
        size_t o = ((size_t)(h * U_ + u0 + r)) * F_ + f0 + c;
        whT[o] = hb;
        wlT[o] = f2bf(v - bf2f(hb));
    }
}

// ---------------- K0: c_src[h,f] = sum_u W[h,f,u]*a_src[h,u]; same for dst ----
__global__ void k0_cvec(const float* __restrict__ W, const float* __restrict__ asr,
                        const float* __restrict__ ads, float* __restrict__ c_src,
                        float* __restrict__ c_dst) {
    int h = blockIdx.x;
    int f = threadIdx.x;
    const float* Wrow = W + ((size_t)h * F_ + f) * U_;
    const float* av = asr + (size_t)h * U_;
    const float* bv = ads + (size_t)h * U_;
    float s = 0.f, d = 0.f;
    for (int u = 0; u < U_; ++u) { float w = Wrow[u]; s += w * av[u]; d += w * bv[u]; }
    c_src[h * F_ + f] = s;
    c_dst[h * F_ + f] = d;
}

// ---------------- K1: h = x @ W[h] via split-bf16 MFMA (3 products, virtual K=768)
__global__ __launch_bounds__(256) void k1_mfma(const unsigned short* __restrict__ xh,
                                               const unsigned short* __restrict__ xl,
                                               const unsigned short* __restrict__ whT,
                                               const unsigned short* __restrict__ wlT,
                                               float* __restrict__ hbuf) {
    __shared__ __align__(16) unsigned short As[128 * 64];
    __shared__ __align__(16) unsigned short Bs[128 * 64];
    const int tid = threadIdx.x;
    const int lane = tid & 63, wv = tid >> 6;
    const int wr = wv >> 1, wc = wv & 1;
    const int m0 = blockIdx.x * 128;
    const int u0 = blockIdx.y * 128;
    const int hh = blockIdx.z;

    floatx4 acc[4][4] = {};

    const char* Ab0 = (const char*)xh;
    const char* Ab1 = (const char*)xl;
    const char* Bb0 = (const char*)(whT + (size_t)hh * U_ * F_);
    const char* Bb2 = (const char*)(wlT + (size_t)hh * U_ * F_);

    // staging geometry: chunk = 1 KB = 8 rows x 128 B; lane -> (row, 16B slot)
    const int ch_row = lane >> 3;
    const int ch_col = (lane & 7) * 16;

    for (int t = 0; t < 12; ++t) {
        const int p = t >> 2;
        const char* Asrc = (p == 1) ? Ab1 : Ab0;
        const char* Bsrc = (p == 2) ? Bb2 : Bb0;
        const size_t kb = (size_t)(t & 3) * 128;     // k0 byte offset within 512 B row
        #pragma unroll
        for (int i = 0; i < 4; ++i) {
            int c = wv * 4 + i;                       // chunk 0..15
            int row = c * 8 + ch_row;
            gload_lds16(Asrc + (size_t)(m0 + row) * 512 + kb + ch_col,
                        (char*)As + c * 1024);
            gload_lds16(Bsrc + (size_t)(u0 + row) * 512 + kb + ch_col,
                        (char*)Bs + c * 1024);
        }
        __syncthreads();
        #pragma unroll
        for (int ks = 0; ks < 2; ++ks) {
            short8 af[4], bfr[4];
            #pragma unroll
            for (int mf = 0; mf < 4; ++mf) {
                int row = wr * 64 + mf * 16 + (lane & 15);
                af[mf] = *(const short8*)&As[row * 64 + ks * 32 + (lane >> 4) * 8];
            }
            #pragma unroll
            for (int nf = 0; nf < 4; ++nf) {
                int row = wc * 64 + nf * 16 + (lane & 15);
                bfr[nf] = *(const short8*)&Bs[row * 64 + ks * 32 + (lane >> 4) * 8];
            }
            #pragma unroll
            for (int mf = 0; mf < 4; ++mf)
                #pragma unroll
                for (int nf = 0; nf < 4; ++nf)
                    acc[mf][nf] = __builtin_amdgcn_mfma_f32_16x16x32_bf16(
                        af[mf], bfr[nf], acc[mf][nf], 0, 0, 0);
        }
        __syncthreads();
    }

    // epilogue: C/D layout col=lane&15, row=(lane>>4)*4+j
    const int rquad = (lane >> 4) * 4;
    const int ucol = lane & 15;
    #pragma unroll
    for (int mf = 0; mf < 4; ++mf) {
        #pragma unroll
        for (int j = 0; j < 4; ++j) {
            int m = m0 + wr * 64 + mf * 16 + rquad + j;
            int b = m >> 10, n = m & 1023;
            float* orow = hbuf + ((size_t)(b * H_ + hh) * N_ + n) * U_ + u0 + wc * 64;
            #pragma unroll
            for (int nf = 0; nf < 4; ++nf)
                orow[nf * 16 + ucol] = acc[mf][nf][j];
        }
    }
}

// ---------------- K1b: src[bh,n] = x[b,n,:].c_src[h,:]; same dst (wave per row) -
__global__ __launch_bounds__(256) void k1b_srcdst(const float* __restrict__ x,
                                                  const float* __restrict__ c_src,
                                                  const float* __restrict__ c_dst,
                                                  float* __restrict__ srcv,
                                                  float* __restrict__ dstv) {
    int tid = threadIdx.x;
    int lane = tid & 63, w = tid >> 6;
    int row = blockIdx.x * 4 + w;
    int b = row >> 10, n = row & 1023;
    const float4 x4 = *(const float4*)(x + (size_t)row * F_ + lane * 4);
    #pragma unroll
    for (int hh = 0; hh < H_; ++hh) {
        float4 c4 = *(const float4*)(c_src + hh * F_ + lane * 4);
        float s = x4.x*c4.x + x4.y*c4.y + x4.z*c4.z + x4.w*c4.w;
        #pragma unroll
        for (int off = 32; off; off >>= 1) s += __shfl_xor(s, off);
        float4 d4 = *(const float4*)(c_dst + hh * F_ + lane * 4);
        float d = x4.x*d4.x + x4.y*d4.y + x4.z*d4.z + x4.w*d4.w;
        #pragma unroll
        for (int off = 32; off; off >>= 1) d += __shfl_xor(d, off);
        if (lane == 0) {
            srcv[(size_t)(b * H_ + hh) * N_ + n] = s;
            dstv[(size_t)(b * H_ + hh) * N_ + n] = d;
        }
    }
}

// ---------------- K2: per-(b,h) bitonic sort of dst values (keys) + index ------
__global__ __launch_bounds__(1024) void k2_sort(const float* __restrict__ dstv,
                                                float* __restrict__ dvs,
                                                int* __restrict__ perm) {
    __shared__ float key[N_];
    __shared__ int   idx[N_];
    int bh = blockIdx.x;
    int t = threadIdx.x;
    key[t] = dstv[(size_t)bh * N_ + t];
    idx[t] = t;
    __syncthreads();
    for (int k = 2; k <= N_; k <<= 1) {
        for (int j = k >> 1; j > 0; j >>= 1) {
            int p = t ^ j;
            if (p > t) {
                float a = key[t], bb = key[p];
                bool up = ((t & k) == 0);
                if (up ? (a > bb) : (a < bb)) {
                    key[t] = bb; key[p] = a;
                    int ti = idx[t]; idx[t] = idx[p]; idx[p] = ti;
                }
            }
            __syncthreads();
        }
    }
    dvs[(size_t)bh * N_ + t] = key[t];
    perm[(size_t)bh * N_ + t] = idx[t];
}

// ---------------- K3a: per-chunk partial sums of w1*h, w2*h ---------------------
__global__ __launch_bounds__(256) void k3a_partial(const float* __restrict__ hbuf,
                                                   const float* __restrict__ dvs,
                                                   const int* __restrict__ perm,
                                                   float* __restrict__ cT1, float* __restrict__ cT2,
                                                   float* __restrict__ cZ1, float* __restrict__ cZ2) {
    int bh = blockIdx.x >> 4;
    int c  = blockIdx.x & 15;
    int u  = threadIdx.x;
    __shared__ float w1s[CH_], w2s[CH_];
    __shared__ int   ps[CH_];
    if (u < CH_) {
        float v = dvs[(size_t)bh * N_ + c * CH_ + u];
        w1s[u] = expf(v);
        w2s[u] = expf(0.2f * v);
        ps[u]  = perm[(size_t)bh * N_ + c * CH_ + u];
    }
    __syncthreads();
    const float* hb = hbuf + (size_t)bh * N_ * U_;
    float a1 = 0.f, a2 = 0.f, z1 = 0.f, z2 = 0.f;
    #pragma unroll 8
    for (int r = 0; r < CH_; ++r) {
        float v = hb[(size_t)ps[r] * U_ + u];
        a1 += w1s[r] * v;
        a2 += w2s[r] * v;
        z1 += w1s[r];
        z2 += w2s[r];
    }
    cT1[(size_t)(bh * NCH_ + c) * U_ + u] = a1;
    cT2[(size_t)(bh * NCH_ + c) * U_ + u] = a2;
    if (u == 0) { cZ1[bh * NCH_ + c] = z1; cZ2[bh * NCH_ + c] = z2; }
}

// ---------------- K3b: chunk-level exclusive prefix (T2) / suffix (T1) bases ----
__global__ __launch_bounds__(256) void k3b_combine(const float* __restrict__ cT1, const float* __restrict__ cT2,
                                                   const float* __restrict__ cZ1, const float* __restrict__ cZ2,
                                                   float* __restrict__ b1, float* __restrict__ b2,
                                                   float* __restrict__ bz1, float* __restrict__ bz2) {
    int bh = blockIdx.x;
    int u = threadIdx.x;
    float acc2 = 0.f;
    for (int c = 0; c < NCH_; ++c) {
        b2[(size_t)(bh * NCH_ + c) * U_ + u] = acc2;
        acc2 += cT2[(size_t)(bh * NCH_ + c) * U_ + u];
    }
    float acc1 = 0.f;
    for (int c = NCH_ - 1; c >= 0; --c) {
        b1[(size_t)(bh * NCH_ + c) * U_ + u] = acc1;
        acc1 += cT1[(size_t)(bh * NCH_ + c) * U_ + u];
    }
    if (u == 0) {
        float z2 = 0.f;
        for (int c = 0; c < NCH_; ++c) { bz2[bh * NCH_ + c] = z2; z2 += cZ2[bh * NCH_ + c]; }
        float z1 = 0.f;
        for (int c = NCH_ - 1; c >= 0; --c) { bz1[bh * NCH_ + c] = z1; z1 += cZ1[bh * NCH_ + c]; }
    }
}

// ---------------- K3c: emit full S1 (suffix incl), S2 (prefix excl), Z1, Z2 -----
__global__ __launch_bounds__(256) void k3c_emit(const float* __restrict__ hbuf,
                                                const float* __restrict__ dvs,
                                                const int* __restrict__ perm,
                                                const float* __restrict__ b1, const float* __restrict__ b2,
                                                const float* __restrict__ bz1, const float* __restrict__ bz2,
                                                float* __restrict__ S1, float* __restrict__ S2,
                                                float* __restrict__ Z1, float* __restrict__ Z2) {
    int bh = blockIdx.x >> 4;
    int c  = blockIdx.x & 15;
    int u  = threadIdx.x;
    __shared__ float w1s[CH_], w2s[CH_];
    __shared__ int   ps[CH_];
    if (u < CH_) {
        float v = dvs[(size_t)bh * N_ + c * CH_ + u];
        w1s[u] = expf(v);
        w2s[u] = expf(0.2f * v);
        ps[u]  = perm[(size_t)bh * N_ + c * CH_ + u];
    }
    __syncthreads();
    const float* hb = hbuf + (size_t)bh * N_ * U_;
    float vals[CH_];
    #pragma unroll
    for (int r = 0; r < CH_; ++r) vals[r] = hb[(size_t)ps[r] * U_ + u];

    size_t rowbase = (size_t)bh * (N_ + 1);
    size_t base = (rowbase + (size_t)c * CH_) * U_;
    float* S2p = S2 + base;
    float* S1p = S1 + base;

    float acc2 = b2[(size_t)(bh * NCH_ + c) * U_ + u];
    float az2  = bz2[bh * NCH_ + c];
    #pragma unroll
    for (int r = 0; r < CH_; ++r) {
        S2p[(size_t)r * U_ + u] = acc2;
        if (u == 0) Z2[rowbase + c * CH_ + r] = az2;
        acc2 += w2s[r] * vals[r];
        az2  += w2s[r];
    }
    if (c == NCH_ - 1) {
        S2p[(size_t)CH_ * U_ + u] = acc2;
        if (u == 0) Z2[rowbase + N_] = az2;
        S1[(rowbase + N_) * U_ + u] = 0.f;
        if (u == 0) Z1[rowbase + N_] = 0.f;
    }

    float acc1 = b1[(size_t)(bh * NCH_ + c) * U_ + u];
    float az1  = bz1[bh * NCH_ + c];
    #pragma unroll
    for (int r = CH_ - 1; r >= 0; --r) {
        acc1 += w1s[r] * vals[r];
        az1  += w1s[r];
        S1p[(size_t)r * U_ + u] = acc1;
        if (u == 0) Z1[rowbase + c * CH_ + r] = az1;
    }
}

// ---------------- K4: per row binary search + combine + write -------------------
__global__ __launch_bounds__(256) void k4_out(const float* __restrict__ srcv,
                                              const float* __restrict__ dvs,
                                              const float* __restrict__ S1, const float* __restrict__ S2,
                                              const float* __restrict__ Z1, const float* __restrict__ Z2,
                                              float* __restrict__ out) {
    int bh = blockIdx.x >> 4;
    int ic = blockIdx.x & 15;
    int b = bh >> 2, hh = bh & 3;
    int u = threadIdx.x;
    __shared__ float dv[N_];
    #pragma unroll
    for (int l = 0; l < 4; ++l) dv[u + l * 256] = dvs[(size_t)bh * N_ + u + l * 256];
    __syncthreads();
    size_t rowbase = (size_t)bh * (N_ + 1);
    for (int ii = 0; ii < 64; ++ii) {
        int i = ic * 64 + ii;
        float s = srcv[(size_t)bh * N_ + i];
        float t = -s;
        int lo = 0, hi = N_;
        while (lo < hi) {
            int mid = (lo + hi) >> 1;
            if (dv[mid] <= t) lo = mid + 1; else hi = mid;
        }
        int pos = lo;
        float e8 = expf(0.8f * s);
        size_t rb = (rowbase + pos) * U_;
        float num = e8 * S1[rb + u] + S2[rb + u];
        float den = e8 * Z1[rowbase + pos] + Z2[rowbase + pos];
        out[((size_t)b * N_ + i) * (H_ * U_) + hh * U_ + u] = num / den;
    }
}

// ---------------- host launch ----------------------------------------------------
extern "C" void kernel_launch(void* const* d_in, const int* in_sizes, int n_in,
                              void* d_out, int out_size, void* d_ws, size_t ws_size,
                              hipStream_t stream) {
    const float* x    = (const float*)d_in[0];
    const float* W    = (const float*)d_in[1];
    const float* asr  = (const float*)d_in[2];
    const float* ads  = (const float*)d_in[3];
    float* out = (float*)d_out;

    char* ws = (char*)d_ws;
    size_t off = 0;
    auto alloc = [&](size_t nfloats) -> float* {
        float* p = (float*)(ws + off);
        off += ((nfloats * 4 + 255) / 256) * 256;
        return p;
    };
    float* hbuf  = alloc((size_t)BH_ * N_ * U_);          // 33.5 MB
    float* srcv  = alloc((size_t)BH_ * N_);
    float* dstv  = alloc((size_t)BH_ * N_);
    float* c_src = alloc(H_ * F_);
    float* c_dst = alloc(H_ * F_);
    float* dvs   = alloc((size_t)BH_ * N_);
    int*   perm  = (int*)alloc((size_t)BH_ * N_);
    float* cT1   = alloc((size_t)BH_ * NCH_ * U_);
    float* cT2   = alloc((size_t)BH_ * NCH_ * U_);
    float* cZ1   = alloc(BH_ * NCH_);
    float* cZ2   = alloc(BH_ * NCH_);
    float* b1    = alloc((size_t)BH_ * NCH_ * U_);
    float* b2    = alloc((size_t)BH_ * NCH_ * U_);
    float* bz1   = alloc(BH_ * NCH_);
    float* bz2   = alloc(BH_ * NCH_);
    float* S1    = alloc((size_t)BH_ * (N_ + 1) * U_);    // 33.6 MB
    float* S2    = alloc((size_t)BH_ * (N_ + 1) * U_);    // 33.6 MB
    float* Z1    = alloc((size_t)BH_ * (N_ + 1));
    float* Z2    = alloc((size_t)BH_ * (N_ + 1));
    unsigned short* xh  = (unsigned short*)alloc((size_t)M_ * F_ / 2);   // 4 MB
    unsigned short* xl  = (unsigned short*)alloc((size_t)M_ * F_ / 2);
    unsigned short* whT = (unsigned short*)alloc((size_t)H_ * U_ * F_ / 2);
    unsigned short* wlT = (unsigned short*)alloc((size_t)H_ * U_ * F_ / 2);
    (void)ws_size; (void)in_sizes; (void)n_in; (void)out_size;

    conv_split<<<(M_ * F_) / (256 * 4), 256, 0, stream>>>(x, xh, xl);
    conv_wT<<<dim3(F_ / 64, U_ / 64, H_), 256, 0, stream>>>(W, whT, wlT);
    k0_cvec<<<H_, 256, 0, stream>>>(W, asr, ads, c_src, c_dst);
    k1_mfma<<<dim3(M_ / 128, U_ / 128, H_), 256, 0, stream>>>(xh, xl, whT, wlT, hbuf);
    k1b_srcdst<<<(B_ * N_) / 4, 256, 0, stream>>>(x, c_src, c_dst, srcv, dstv);
    k2_sort<<<BH_, 1024, 0, stream>>>(dstv, dvs, perm);
    k3a_partial<<<BH_ * NCH_, 256, 0, stream>>>(hbuf, dvs, perm, cT1, cT2, cZ1, cZ2);
    k3b_combine<<<BH_, 256, 0, stream>>>(cT1, cT2, cZ1, cZ2, b1, b2, bz1, bz2);
    k3c_emit<<<BH_ * NCH_, 256, 0, stream>>>(hbuf, dvs, perm, b1, b2, bz1, bz2, S1, S2, Z1, Z2);
    k4_out<<<BH_ * NCH_, 256, 0, stream>>>(srcv, dvs, S1, S2, Z1, Z2, out);
}

// Round 3
// 112.259 us; speedup vs baseline: 1.7387x; 1.4503x over previous
//
#include <hip/hip_runtime.h>
#include <math.h>

constexpr int B_ = 8, N_ = 1024, F_ = 256, H_ = 4, U_ = 256;
constexpr int BH_ = B_ * H_;
constexpr int CH_ = 64;          // scan chunk length
constexpr int NCH_ = N_ / CH_;   // 16 chunks
constexpr int M_ = B_ * N_;      // 8192 GEMM rows per head

typedef short short8 __attribute__((ext_vector_type(8)));
typedef float floatx4 __attribute__((ext_vector_type(4)));

__device__ inline unsigned short f2bf(float f) {
    unsigned u = __float_as_uint(f);
    u += 0x7fff + ((u >> 16) & 1);          // round-to-nearest-even
    return (unsigned short)(u >> 16);
}
__device__ inline float bf2f(unsigned short s) { return __uint_as_float(((unsigned)s) << 16); }

__device__ inline void gload_lds16(const void* g, void* l) {
    __builtin_amdgcn_global_load_lds(
        (const __attribute__((address_space(1))) void*)g,
        (__attribute__((address_space(3))) void*)(unsigned)(uintptr_t)l,
        16, 0, 0);
}

// ---------------- conv: split fp32 -> bf16 hi + bf16 lo (elementwise, x) -------
__global__ __launch_bounds__(256) void conv_split(const float* __restrict__ in,
                                                  unsigned short* __restrict__ hi,
                                                  unsigned short* __restrict__ lo) {
    int i = blockIdx.x * 256 + threadIdx.x;
    float4 v = ((const float4*)in)[i];
    ushort4 h, l;
    h.x = f2bf(v.x); l.x = f2bf(v.x - bf2f(h.x));
    h.y = f2bf(v.y); l.y = f2bf(v.y - bf2f(h.y));
    h.z = f2bf(v.z); l.z = f2bf(v.z - bf2f(h.z));
    h.w = f2bf(v.w); l.w = f2bf(v.w - bf2f(h.w));
    ((ushort4*)hi)[i] = h;
    ((ushort4*)lo)[i] = l;
}

// ---------------- convT: W[h,f,u] fp32 -> WT[h,u,f] bf16 hi/lo (tiled transpose)
__global__ __launch_bounds__(256) void conv_wT(const float* __restrict__ W,
                                               unsigned short* __restrict__ whT,
                                               unsigned short* __restrict__ wlT) {
    __shared__ float t[64][65];
    int h = blockIdx.z, f0 = blockIdx.x * 64, u0 = blockIdx.y * 64;
    int tid = threadIdx.x;
    int c = tid & 63, rbase = tid >> 6;
    #pragma unroll
    for (int rr = 0; rr < 16; ++rr) {
        int r = rr * 4 + rbase;
        t[r][c] = W[((size_t)(h * F_ + f0 + r)) * U_ + u0 + c];
    }
    __syncthreads();
    #pragma unroll
    for (int rr = 0; rr < 16; ++rr) {
        int r = rr * 4 + rbase;                 // u-local
        float v = t[c][r];                      // W[f0+c][u0+r]
        unsigned short hb = f2bf(v);
        size_t o = ((size_t)(h * U_ + u0 + r)) * F_ + f0 + c;
        whT[o] = hb;
        wlT[o] = f2bf(v - bf2f(hb));
    }
}

// ---------------- K0: c_src[h,f] = sum_u W[h,f,u]*a_src[h,u]; same for dst ----
__global__ void k0_cvec(const float* __restrict__ W, const float* __restrict__ asr,
                        const float* __restrict__ ads, float* __restrict__ c_src,
                        float* __restrict__ c_dst) {
    int h = blockIdx.x;
    int f = threadIdx.x;
    const float* Wrow = W + ((size_t)h * F_ + f) * U_;
    const float* av = asr + (size_t)h * U_;
    const float* bv = ads + (size_t)h * U_;
    float s = 0.f, d = 0.f;
    for (int u = 0; u < U_; ++u) { float w = Wrow[u]; s += w * av[u]; d += w * bv[u]; }
    c_src[h * F_ + f] = s;
    c_dst[h * F_ + f] = d;
}

// ---------------- K1: h = x @ W[h] via split-bf16 MFMA (3 products, virtual K=768)
__global__ __launch_bounds__(256) void k1_mfma(const unsigned short* __restrict__ xh,
                                               const unsigned short* __restrict__ xl,
                                               const unsigned short* __restrict__ whT,
                                               const unsigned short* __restrict__ wlT,
                                               float* __restrict__ hbuf) {
    __shared__ __align__(16) unsigned short As[128 * 64];
    __shared__ __align__(16) unsigned short Bs[128 * 64];
    const int tid = threadIdx.x;
    const int lane = tid & 63, wv = tid >> 6;
    const int wr = wv >> 1, wc = wv & 1;
    const int m0 = blockIdx.x * 128;
    const int u0 = blockIdx.y * 128;
    const int hh = blockIdx.z;

    floatx4 acc[4][4] = {};

    const char* Ab0 = (const char*)xh;
    const char* Ab1 = (const char*)xl;
    const char* Bb0 = (const char*)(whT + (size_t)hh * U_ * F_);
    const char* Bb2 = (const char*)(wlT + (size_t)hh * U_ * F_);

    const int ch_row = lane >> 3;
    const int ch_col = (lane & 7) * 16;

    for (int t = 0; t < 12; ++t) {
        const int p = t >> 2;
        const char* Asrc = (p == 1) ? Ab1 : Ab0;
        const char* Bsrc = (p == 2) ? Bb2 : Bb0;
        const size_t kb = (size_t)(t & 3) * 128;
        #pragma unroll
        for (int i = 0; i < 4; ++i) {
            int c = wv * 4 + i;
            int row = c * 8 + ch_row;
            gload_lds16(Asrc + (size_t)(m0 + row) * 512 + kb + ch_col,
                        (char*)As + c * 1024);
            gload_lds16(Bsrc + (size_t)(u0 + row) * 512 + kb + ch_col,
                        (char*)Bs + c * 1024);
        }
        __syncthreads();
        #pragma unroll
        for (int ks = 0; ks < 2; ++ks) {
            short8 af[4], bfr[4];
            #pragma unroll
            for (int mf = 0; mf < 4; ++mf) {
                int row = wr * 64 + mf * 16 + (lane & 15);
                af[mf] = *(const short8*)&As[row * 64 + ks * 32 + (lane >> 4) * 8];
            }
            #pragma unroll
            for (int nf = 0; nf < 4; ++nf) {
                int row = wc * 64 + nf * 16 + (lane & 15);
                bfr[nf] = *(const short8*)&Bs[row * 64 + ks * 32 + (lane >> 4) * 8];
            }
            #pragma unroll
            for (int mf = 0; mf < 4; ++mf)
                #pragma unroll
                for (int nf = 0; nf < 4; ++nf)
                    acc[mf][nf] = __builtin_amdgcn_mfma_f32_16x16x32_bf16(
                        af[mf], bfr[nf], acc[mf][nf], 0, 0, 0);
        }
        __syncthreads();
    }

    const int rquad = (lane >> 4) * 4;
    const int ucol = lane & 15;
    #pragma unroll
    for (int mf = 0; mf < 4; ++mf) {
        #pragma unroll
        for (int j = 0; j < 4; ++j) {
            int m = m0 + wr * 64 + mf * 16 + rquad + j;
            int b = m >> 10, n = m & 1023;
            float* orow = hbuf + ((size_t)(b * H_ + hh) * N_ + n) * U_ + u0 + wc * 64;
            #pragma unroll
            for (int nf = 0; nf < 4; ++nf)
                orow[nf * 16 + ucol] = acc[mf][nf][j];
        }
    }
}

// ---------------- K1b: src[bh,n] = x[b,n,:].c_src[h,:]; same dst (wave per row) -
__global__ __launch_bounds__(256) void k1b_srcdst(const float* __restrict__ x,
                                                  const float* __restrict__ c_src,
                                                  const float* __restrict__ c_dst,
                                                  float* __restrict__ srcv,
                                                  float* __restrict__ dstv) {
    int tid = threadIdx.x;
    int lane = tid & 63, w = tid >> 6;
    int row = blockIdx.x * 4 + w;
    int b = row >> 10, n = row & 1023;
    const float4 x4 = *(const float4*)(x + (size_t)row * F_ + lane * 4);
    #pragma unroll
    for (int hh = 0; hh < H_; ++hh) {
        float4 c4 = *(const float4*)(c_src + hh * F_ + lane * 4);
        float s = x4.x*c4.x + x4.y*c4.y + x4.z*c4.z + x4.w*c4.w;
        #pragma unroll
        for (int off = 32; off; off >>= 1) s += __shfl_xor(s, off);
        float4 d4 = *(const float4*)(c_dst + hh * F_ + lane * 4);
        float d = x4.x*d4.x + x4.y*d4.y + x4.z*d4.z + x4.w*d4.w;
        #pragma unroll
        for (int off = 32; off; off >>= 1) d += __shfl_xor(d, off);
        if (lane == 0) {
            srcv[(size_t)(b * H_ + hh) * N_ + n] = s;
            dstv[(size_t)(b * H_ + hh) * N_ + n] = d;
        }
    }
}

// ---------------- K2: per-(b,h) bitonic sort of dst + per-row pos/e8 -----------
__global__ __launch_bounds__(1024) void k2_sort(const float* __restrict__ dstv,
                                                const float* __restrict__ srcv,
                                                float* __restrict__ dvs,
                                                int* __restrict__ perm,
                                                int* __restrict__ posb,
                                                float* __restrict__ e8b) {
    __shared__ float key[N_];
    __shared__ int   idx[N_];
    int bh = blockIdx.x;
    int t = threadIdx.x;
    key[t] = dstv[(size_t)bh * N_ + t];
    idx[t] = t;
    __syncthreads();
    for (int k = 2; k <= N_; k <<= 1) {
        for (int j = k >> 1; j > 0; j >>= 1) {
            int p = t ^ j;
            if (p > t) {
                float a = key[t], bb = key[p];
                bool up = ((t & k) == 0);
                if (up ? (a > bb) : (a < bb)) {
                    key[t] = bb; key[p] = a;
                    int ti = idx[t]; idx[t] = idx[p]; idx[p] = ti;
                }
            }
            __syncthreads();
        }
    }
    dvs[(size_t)bh * N_ + t] = key[t];
    perm[(size_t)bh * N_ + t] = idx[t];
    // per-row split point + src exponent (key[] is final; no further LDS writes)
    float s = srcv[(size_t)bh * N_ + t];
    float tt = -s;
    int lo = 0, hi = N_;
    while (lo < hi) {                 // exactly 10 iterations
        int mid = (lo + hi) >> 1;
        if (key[mid] <= tt) lo = mid + 1; else hi = mid;
    }
    posb[(size_t)bh * N_ + t] = lo;
    e8b[(size_t)bh * N_ + t]  = expf(0.8f * s);
}

// ---------------- K3a: per-chunk partial sums of w1*h, w2*h ---------------------
__global__ __launch_bounds__(256) void k3a_partial(const float* __restrict__ hbuf,
                                                   const float* __restrict__ dvs,
                                                   const int* __restrict__ perm,
                                                   float* __restrict__ cT1, float* __restrict__ cT2,
                                                   float* __restrict__ cZ1, float* __restrict__ cZ2) {
    int bh = blockIdx.x >> 4;
    int c  = blockIdx.x & 15;
    int u  = threadIdx.x;
    __shared__ float w1s[CH_], w2s[CH_];
    __shared__ int   ps[CH_];
    if (u < CH_) {
        float v = dvs[(size_t)bh * N_ + c * CH_ + u];
        w1s[u] = expf(v);
        w2s[u] = expf(0.2f * v);
        ps[u]  = perm[(size_t)bh * N_ + c * CH_ + u];
    }
    __syncthreads();
    const float* hb = hbuf + (size_t)bh * N_ * U_;
    float a1 = 0.f, a2 = 0.f, z1 = 0.f, z2 = 0.f;
    #pragma unroll 8
    for (int r = 0; r < CH_; ++r) {
        float v = hb[(size_t)ps[r] * U_ + u];
        a1 += w1s[r] * v;
        a2 += w2s[r] * v;
        z1 += w1s[r];
        z2 += w2s[r];
    }
    cT1[(size_t)(bh * NCH_ + c) * U_ + u] = a1;
    cT2[(size_t)(bh * NCH_ + c) * U_ + u] = a2;
    if (u == 0) { cZ1[bh * NCH_ + c] = z1; cZ2[bh * NCH_ + c] = z2; }
}

// ---------------- K3b: chunk-level exclusive prefix (T2) / suffix (T1) bases ----
__global__ __launch_bounds__(256) void k3b_combine(const float* __restrict__ cT1, const float* __restrict__ cT2,
                                                   const float* __restrict__ cZ1, const float* __restrict__ cZ2,
                                                   float* __restrict__ b1, float* __restrict__ b2,
                                                   float* __restrict__ bz1, float* __restrict__ bz2) {
    int bh = blockIdx.x;
    int u = threadIdx.x;
    float acc2 = 0.f;
    for (int c = 0; c < NCH_; ++c) {
        b2[(size_t)(bh * NCH_ + c) * U_ + u] = acc2;
        acc2 += cT2[(size_t)(bh * NCH_ + c) * U_ + u];
    }
    float acc1 = 0.f;
    for (int c = NCH_ - 1; c >= 0; --c) {
        b1[(size_t)(bh * NCH_ + c) * U_ + u] = acc1;
        acc1 += cT1[(size_t)(bh * NCH_ + c) * U_ + u];
    }
    if (u == 0) {
        float z2 = 0.f;
        for (int c = 0; c < NCH_; ++c) { bz2[bh * NCH_ + c] = z2; z2 += cZ2[bh * NCH_ + c]; }
        float z1 = 0.f;
        for (int c = NCH_ - 1; c >= 0; --c) { bz1[bh * NCH_ + c] = z1; z1 += cZ1[bh * NCH_ + c]; }
    }
}

// ---------------- K3c: emit interleaved S12 (S1 suffix incl | S2 prefix excl) ---
__global__ __launch_bounds__(256) void k3c_emit(const float* __restrict__ hbuf,
                                                const float* __restrict__ dvs,
                                                const int* __restrict__ perm,
                                                const float* __restrict__ b1, const float* __restrict__ b2,
                                                const float* __restrict__ bz1, const float* __restrict__ bz2,
                                                float* __restrict__ S12,
                                                float* __restrict__ Z1, float* __restrict__ Z2) {
    int bh = blockIdx.x >> 4;
    int c  = blockIdx.x & 15;
    int u  = threadIdx.x;
    __shared__ float w1s[CH_], w2s[CH_];
    __shared__ int   ps[CH_];
    if (u < CH_) {
        float v = dvs[(size_t)bh * N_ + c * CH_ + u];
        w1s[u] = expf(v);
        w2s[u] = expf(0.2f * v);
        ps[u]  = perm[(size_t)bh * N_ + c * CH_ + u];
    }
    __syncthreads();
    const float* hb = hbuf + (size_t)bh * N_ * U_;
    float vals[CH_];
    #pragma unroll
    for (int r = 0; r < CH_; ++r) vals[r] = hb[(size_t)ps[r] * U_ + u];

    size_t rowbase = (size_t)bh * (N_ + 1);
    float* Sp = S12 + (rowbase + (size_t)c * CH_) * (2 * U_);

    float acc2 = b2[(size_t)(bh * NCH_ + c) * U_ + u];
    float az2  = bz2[bh * NCH_ + c];
    #pragma unroll
    for (int r = 0; r < CH_; ++r) {
        Sp[(size_t)r * (2 * U_) + U_ + u] = acc2;
        if (u == 0) Z2[rowbase + c * CH_ + r] = az2;
        acc2 += w2s[r] * vals[r];
        az2  += w2s[r];
    }
    if (c == NCH_ - 1) {
        Sp[(size_t)CH_ * (2 * U_) + U_ + u] = acc2;      // row N (all branch-2)
        Sp[(size_t)CH_ * (2 * U_) + u]      = 0.f;       // row N suffix empty
        if (u == 0) { Z2[rowbase + N_] = az2; Z1[rowbase + N_] = 0.f; }
    }

    float acc1 = b1[(size_t)(bh * NCH_ + c) * U_ + u];
    float az1  = bz1[bh * NCH_ + c];
    #pragma unroll
    for (int r = CH_ - 1; r >= 0; --r) {
        acc1 += w1s[r] * vals[r];
        az1  += w1s[r];
        Sp[(size_t)r * (2 * U_) + u] = acc1;
        if (u == 0) Z1[rowbase + c * CH_ + r] = az1;
    }
}

// ---------------- K4: pure gather — 8 rows per block, no search ------------------
__global__ __launch_bounds__(256) void k4_out(const int* __restrict__ posb,
                                              const float* __restrict__ e8b,
                                              const float* __restrict__ Z1,
                                              const float* __restrict__ Z2,
                                              const float* __restrict__ S12,
                                              float* __restrict__ out) {
    int blk = blockIdx.x;
    int bh = blk >> 7;                 // 128 blocks per bh
    int r0 = (blk & 127) * 8;
    int b = bh >> 2, hh = bh & 3;
    int u = threadIdx.x;
    size_t obase   = (size_t)bh * N_;
    size_t rowbase = (size_t)bh * (N_ + 1);

    int pos[8]; float e8[8];
    #pragma unroll
    for (int r = 0; r < 8; ++r) {
        pos[r] = posb[obase + r0 + r];
        e8[r]  = e8b[obase + r0 + r];
    }
    float idn[8];
    #pragma unroll
    for (int r = 0; r < 8; ++r) {
        float z1 = Z1[rowbase + pos[r]];
        float z2 = Z2[rowbase + pos[r]];
        idn[r] = 1.0f / (e8[r] * z1 + z2);
    }
    float s1[8], s2[8];
    #pragma unroll
    for (int r = 0; r < 8; ++r) {
        const float* Sp = S12 + (rowbase + (size_t)pos[r]) * (2 * U_);
        s1[r] = Sp[u];
        s2[r] = Sp[U_ + u];
    }
    #pragma unroll
    for (int r = 0; r < 8; ++r) {
        int i = r0 + r;
        out[((size_t)b * N_ + i) * (H_ * U_) + hh * U_ + u] = (e8[r] * s1[r] + s2[r]) * idn[r];
    }
}

// ---------------- host launch ----------------------------------------------------
extern "C" void kernel_launch(void* const* d_in, const int* in_sizes, int n_in,
                              void* d_out, int out_size, void* d_ws, size_t ws_size,
                              hipStream_t stream) {
    const float* x    = (const float*)d_in[0];
    const float* W    = (const float*)d_in[1];
    const float* asr  = (const float*)d_in[2];
    const float* ads  = (const float*)d_in[3];
    float* out = (float*)d_out;

    char* ws = (char*)d_ws;
    size_t off = 0;
    auto alloc = [&](size_t nfloats) -> float* {
        float* p = (float*)(ws + off);
        off += ((nfloats * 4 + 255) / 256) * 256;
        return p;
    };
    float* hbuf  = alloc((size_t)BH_ * N_ * U_);          // 33.5 MB
    float* srcv  = alloc((size_t)BH_ * N_);
    float* dstv  = alloc((size_t)BH_ * N_);
    float* c_src = alloc(H_ * F_);
    float* c_dst = alloc(H_ * F_);
    float* dvs   = alloc((size_t)BH_ * N_);
    int*   perm  = (int*)alloc((size_t)BH_ * N_);
    int*   posb  = (int*)alloc((size_t)BH_ * N_);
    float* e8b   = alloc((size_t)BH_ * N_);
    float* cT1   = alloc((size_t)BH_ * NCH_ * U_);
    float* cT2   = alloc((size_t)BH_ * NCH_ * U_);
    float* cZ1   = alloc(BH_ * NCH_);
    float* cZ2   = alloc(BH_ * NCH_);
    float* b1    = alloc((size_t)BH_ * NCH_ * U_);
    float* b2    = alloc((size_t)BH_ * NCH_ * U_);
    float* bz1   = alloc(BH_ * NCH_);
    float* bz2   = alloc(BH_ * NCH_);
    float* S12   = alloc((size_t)BH_ * (N_ + 1) * 2 * U_); // 67.2 MB interleaved
    float* Z1    = alloc((size_t)BH_ * (N_ + 1));
    float* Z2    = alloc((size_t)BH_ * (N_ + 1));
    unsigned short* xh  = (unsigned short*)alloc((size_t)M_ * F_ / 2);
    unsigned short* xl  = (unsigned short*)alloc((size_t)M_ * F_ / 2);
    unsigned short* whT = (unsigned short*)alloc((size_t)H_ * U_ * F_ / 2);
    unsigned short* wlT = (unsigned short*)alloc((size_t)H_ * U_ * F_ / 2);
    (void)ws_size; (void)in_sizes; (void)n_in; (void)out_size;

    conv_split<<<(M_ * F_) / (256 * 4), 256, 0, stream>>>(x, xh, xl);
    conv_wT<<<dim3(F_ / 64, U_ / 64, H_), 256, 0, stream>>>(W, whT, wlT);
    k0_cvec<<<H_, 256, 0, stream>>>(W, asr, ads, c_src, c_dst);
    k1b_srcdst<<<(B_ * N_) / 4, 256, 0, stream>>>(x, c_src, c_dst, srcv, dstv);
    k2_sort<<<BH_, 1024, 0, stream>>>(dstv, srcv, dvs, perm, posb, e8b);
    k1_mfma<<<dim3(M_ / 128, U_ / 128, H_), 256, 0, stream>>>(xh, xl, whT, wlT, hbuf);
    k3a_partial<<<BH_ * NCH_, 256, 0, stream>>>(hbuf, dvs, perm, cT1, cT2, cZ1, cZ2);
    k3b_combine<<<BH_, 256, 0, stream>>>(cT1, cT2, cZ1, cZ2, b1, b2, bz1, bz2);
    k3c_emit<<<BH_ * NCH_, 256, 0, stream>>>(hbuf, dvs, perm, b1, b2, bz1, bz2, S12, Z1, Z2);
    k4_out<<<BH_ * N_ / 8, 256, 0, stream>>>(posb, e8b, Z1, Z2, S12, out);
}